// Round 2
// baseline (4798.735 us; speedup 1.0000x reference)
//
#include <hip/hip_runtime.h>
#include <hip/hip_bf16.h>
#include <math.h>

#define N_NODES 50000
#define N_EDGES 400000
#define HEADS 6
#define DIMS 32
#define FEAT 192
#define NEG_SLOPE 0.2f
#define E_TOT (N_EDGES + N_NODES)

// ---------------- workspace layout (fp32 elements) ----------------
// [outacc: N*192][cnt: N][wsum: N][denom: N*6]  <- zeroed via one memset
// then xl (fp32, N*192), xr (fp32, N*192)
#define OFF_OUTACC 0
#define OFF_CNT    (N_NODES * FEAT)                 // 9,600,000
#define OFF_WSUM   (OFF_CNT + N_NODES)              // 9,650,000
#define OFF_DENOM  (OFF_WSUM + N_NODES)             // 9,700,000
#define ZERO_FLOATS (OFF_DENOM + N_NODES * HEADS)   // 10,000,000
#define OFF_XL  ZERO_FLOATS                         // 10,000,000
#define OFF_XR  (OFF_XL + N_NODES * FEAT)           // 19,600,000

// ---------------- pass 1: per-node incoming count + weight sum ----------------
__global__ __launch_bounds__(256) void k_edge_stats(const int* __restrict__ ei,
                                                    const float* __restrict__ ew,
                                                    float* __restrict__ cnt,
                                                    float* __restrict__ wsum) {
    int e = blockIdx.x * blockDim.x + threadIdx.x;
    if (e < N_EDGES) {
        int d = ei[N_EDGES + e];
        unsafeAtomicAdd(&cnt[d], 1.0f);
        unsafeAtomicAdd(&wsum[d], ew[e]);
    }
}

// ---------------- pass 2: xl = x@Wl + bl, xr = x@Wr + br ----------------
// 192 threads = one output column each; 16 rows register-blocked per thread.
// x tile transposed in LDS (stride 20 floats keeps ds_read_b128 16B-aligned).
#define GROWS 16
#define XS_STRIDE 20
__global__ __launch_bounds__(192) void k_gemm(const float* __restrict__ x,
                                              const float* __restrict__ Wl,
                                              const float* __restrict__ bl,
                                              const float* __restrict__ Wr,
                                              const float* __restrict__ br,
                                              float* __restrict__ xl,
                                              float* __restrict__ xr) {
    __shared__ float xsT[FEAT * XS_STRIDE];  // xsT[k*20 + r] = x[row0+r][k]
    int j = threadIdx.x;                      // output column 0..191
    int row0 = blockIdx.x * GROWS;
    int nrows = N_NODES - row0; if (nrows > GROWS) nrows = GROWS;
    for (int r = 0; r < nrows; r++) {
        xsT[j * XS_STRIDE + r] = x[(size_t)(row0 + r) * FEAT + j];
    }
    __syncthreads();

    float al[GROWS], ar[GROWS];
    float blj = bl[j], brj = br[j];
#pragma unroll
    for (int r = 0; r < GROWS; r++) { al[r] = blj; ar[r] = brj; }

    for (int k = 0; k < FEAT; k++) {
        float wl = Wl[k * FEAT + j];
        float wr = Wr[k * FEAT + j];
        const float4* xc = reinterpret_cast<const float4*>(&xsT[k * XS_STRIDE]);
        float4 x0 = xc[0], x1 = xc[1], x2 = xc[2], x3 = xc[3];
        const float* xv = reinterpret_cast<const float*>(&x0);
#pragma unroll
        for (int r = 0; r < 4; r++)  { al[r] += xv[r] * wl;  ar[r] += xv[r] * wr; }
        const float* xv1 = reinterpret_cast<const float*>(&x1);
#pragma unroll
        for (int r = 0; r < 4; r++)  { al[4+r] += xv1[r] * wl; ar[4+r] += xv1[r] * wr; }
        const float* xv2 = reinterpret_cast<const float*>(&x2);
#pragma unroll
        for (int r = 0; r < 4; r++)  { al[8+r] += xv2[r] * wl; ar[8+r] += xv2[r] * wr; }
        const float* xv3 = reinterpret_cast<const float*>(&x3);
#pragma unroll
        for (int r = 0; r < 4; r++)  { al[12+r] += xv3[r] * wl; ar[12+r] += xv3[r] * wr; }
    }

    for (int r = 0; r < nrows; r++) {
        xl[(size_t)(row0 + r) * FEAT + j] = al[r];
        xr[(size_t)(row0 + r) * FEAT + j] = ar[r];
    }
}

// ---------------- pass 3: fused edge scoring + exp + denom + message scatter ----------------
// one thread per (edge, head); softmax max-subtraction skipped: alpha std~1.9,
// max over 2.7M samples ~ +-11 -> exp safe in fp32.
__global__ __launch_bounds__(256) void k_edge(const int* __restrict__ ei,
                                              const float* __restrict__ ew,
                                              const float* __restrict__ att,
                                              const float* __restrict__ We,
                                              const float* __restrict__ cnt,
                                              const float* __restrict__ wsum,
                                              const float* __restrict__ xl,
                                              const float* __restrict__ xr,
                                              float* __restrict__ denom,
                                              float* __restrict__ outacc) {
    __shared__ float satt[FEAT], sWe[FEAT];
    int t = threadIdx.x;
    if (t < FEAT) { satt[t] = att[t]; sWe[t] = We[t]; }
    __syncthreads();

    int gid = blockIdx.x * blockDim.x + t;
    if (gid >= E_TOT * HEADS) return;
    int e = gid / HEADS;
    int h = gid - e * HEADS;

    int s, d;
    float w;
    if (e < N_EDGES) {
        s = ei[e];
        d = ei[N_EDGES + e];
        w = ew[e];
    } else {
        int n = e - N_EDGES;
        s = n; d = n;
        w = wsum[n] / fmaxf(cnt[n], 1.0f);
    }

    const float4* pl = reinterpret_cast<const float4*>(xl + (size_t)s * FEAT + h * DIMS);
    const float4* pr = reinterpret_cast<const float4*>(xr + (size_t)d * FEAT + h * DIMS);

    float lv[DIMS];
    float alpha = 0.f;
#pragma unroll
    for (int q = 0; q < 8; q++) {
        float4 a4 = pl[q];
        float4 b4 = pr[q];
        const float* la = reinterpret_cast<const float*>(&a4);
        const float* lb = reinterpret_cast<const float*>(&b4);
#pragma unroll
        for (int u = 0; u < 4; u++) {
            int c = q * 4 + u;
            float lvv = la[u];
            float m = lvv + lb[u] + w * sWe[h * DIMS + c];
            m = (m > 0.f) ? m : NEG_SLOPE * m;
            alpha += m * satt[h * DIMS + c];
            lv[c] = lvv;
        }
    }
    float ex = __expf(alpha);
    unsafeAtomicAdd(&denom[d * HEADS + h], ex);
    float* po = outacc + (size_t)d * FEAT + h * DIMS;
#pragma unroll
    for (int c = 0; c < DIMS; c++) unsafeAtomicAdd(&po[c], ex * lv[c]);
}

// ---------------- pass 4: out = relu(x + bias + outacc/denom) ----------------
__global__ __launch_bounds__(256) void k_final(const float* __restrict__ x,
                                               const float* __restrict__ bias,
                                               const float* __restrict__ outacc,
                                               const float* __restrict__ denom,
                                               float* __restrict__ out) {
    int i = blockIdx.x * blockDim.x + threadIdx.x;
    if (i < N_NODES * FEAT) {
        int n = i / FEAT;
        int j = i - n * FEAT;
        int h = j >> 5;
        float v = x[i] + bias[j] + outacc[i] / denom[n * HEADS + h];
        out[i] = v > 0.f ? v : 0.f;
    }
}

extern "C" void kernel_launch(void* const* d_in, const int* in_sizes, int n_in,
                              void* d_out, int out_size, void* d_ws, size_t ws_size,
                              hipStream_t stream) {
    const float* x    = (const float*)d_in[0];
    const int*   ei   = (const int*)d_in[1];
    const float* ew   = (const float*)d_in[2];
    const float* Wl   = (const float*)d_in[3];
    const float* bl   = (const float*)d_in[4];
    const float* Wr   = (const float*)d_in[5];
    const float* br   = (const float*)d_in[6];
    const float* We   = (const float*)d_in[7];
    const float* att  = (const float*)d_in[8];
    const float* bias = (const float*)d_in[9];
    float* out = (float*)d_out;

    float* wsf = (float*)d_ws;
    float* outacc = wsf + OFF_OUTACC;
    float* cnt    = wsf + OFF_CNT;
    float* wsum   = wsf + OFF_WSUM;
    float* denom  = wsf + OFF_DENOM;
    float* xl     = wsf + OFF_XL;
    float* xr     = wsf + OFF_XR;

    // zero the accumulator region (harness poisons ws with 0xAA)
    hipMemsetAsync(d_ws, 0, (size_t)ZERO_FLOATS * sizeof(float), stream);

    k_edge_stats<<<(N_EDGES + 255) / 256, 256, 0, stream>>>(ei, ew, cnt, wsum);

    k_gemm<<<(N_NODES + GROWS - 1) / GROWS, 192, 0, stream>>>(x, Wl, bl, Wr, br, xl, xr);

    k_edge<<<((size_t)E_TOT * HEADS + 255) / 256, 256, 0, stream>>>(ei, ew, att, We, cnt, wsum,
                                                                    xl, xr, denom, outacc);

    k_final<<<(N_NODES * FEAT + 255) / 256, 256, 0, stream>>>(x, bias, outacc, denom, out);
}

// Round 3
// 414.741 us; speedup vs baseline: 11.5704x; 11.5704x over previous
//
#include <hip/hip_runtime.h>
#include <hip/hip_bf16.h>
#include <math.h>

#define N_NODES 50000
#define N_EDGES 400000
#define HEADS 6
#define DIMS 32
#define FEAT 192
#define NEG_SLOPE 0.2f

// ---------------- workspace layout ----------------
// floats: [xl: N*192][xr: N*192]
// ints (after floats): [deg: N][cursor: N][start: N][scan: N][bsums: 256][boffs: 256][col: E]
#define OFF_XL 0
#define OFF_XR (N_NODES * FEAT)
#define IDX_BASE (N_NODES * FEAT * 2)
#define NB_SCAN ((N_NODES + 255) / 256)   // 196

// ---------------- CSR build ----------------
__global__ __launch_bounds__(256) void k_count(const int* __restrict__ ei,
                                               int* __restrict__ deg) {
    int e = blockIdx.x * blockDim.x + threadIdx.x;
    if (e < N_EDGES) atomicAdd(&deg[ei[N_EDGES + e]], 1);
}

__global__ __launch_bounds__(256) void k_scan1(const int* __restrict__ deg,
                                               int* __restrict__ scan,
                                               int* __restrict__ bsums) {
    int t = threadIdx.x;
    int i = blockIdx.x * 256 + t;
    int v = (i < N_NODES) ? deg[i] : 0;
    __shared__ int s[256];
    s[t] = v; __syncthreads();
    for (int off = 1; off < 256; off <<= 1) {
        int u = (t >= off) ? s[t - off] : 0;
        __syncthreads();
        s[t] += u;
        __syncthreads();
    }
    if (i < N_NODES) scan[i] = s[t];
    if (t == 255) bsums[blockIdx.x] = s[255];
}

__global__ __launch_bounds__(256) void k_scan2(int* __restrict__ bsums,
                                               int* __restrict__ boffs) {
    int t = threadIdx.x;
    int v = (t < NB_SCAN) ? bsums[t] : 0;
    __shared__ int s[256];
    s[t] = v; __syncthreads();
    for (int off = 1; off < 256; off <<= 1) {
        int u = (t >= off) ? s[t - off] : 0;
        __syncthreads();
        s[t] += u;
        __syncthreads();
    }
    boffs[t] = s[t] - v;   // exclusive
}

__global__ __launch_bounds__(256) void k_scan3(const int* __restrict__ scan,
                                               const int* __restrict__ boffs,
                                               const int* __restrict__ deg,
                                               int* __restrict__ start) {
    int i = blockIdx.x * blockDim.x + threadIdx.x;
    if (i < N_NODES) start[i] = scan[i] + boffs[i >> 8] - deg[i];
}

__global__ __launch_bounds__(256) void k_scatter(const int* __restrict__ ei,
                                                 const int* __restrict__ start,
                                                 int* __restrict__ cursor,
                                                 int* __restrict__ col) {
    int e = blockIdx.x * blockDim.x + threadIdx.x;
    if (e < N_EDGES) {
        int d = ei[N_EDGES + e];
        int slot = atomicAdd(&cursor[d], 1);
        col[start[d] + slot] = e;
    }
}

// ---------------- xl = x@Wl + bl, xr = x@Wr + br ----------------
#define GROWS 16
#define XS_STRIDE 20
__global__ __launch_bounds__(192) void k_gemm(const float* __restrict__ x,
                                              const float* __restrict__ Wl,
                                              const float* __restrict__ bl,
                                              const float* __restrict__ Wr,
                                              const float* __restrict__ br,
                                              float* __restrict__ xl,
                                              float* __restrict__ xr) {
    __shared__ float xsT[FEAT * XS_STRIDE];  // xsT[k*20 + r] = x[row0+r][k]
    int j = threadIdx.x;                      // output column 0..191
    int row0 = blockIdx.x * GROWS;
    int nrows = N_NODES - row0; if (nrows > GROWS) nrows = GROWS;
    for (int r = 0; r < nrows; r++) {
        xsT[j * XS_STRIDE + r] = x[(size_t)(row0 + r) * FEAT + j];
    }
    __syncthreads();

    float al[GROWS], ar[GROWS];
    float blj = bl[j], brj = br[j];
#pragma unroll
    for (int r = 0; r < GROWS; r++) { al[r] = blj; ar[r] = brj; }

    for (int k = 0; k < FEAT; k++) {
        float wl = Wl[k * FEAT + j];
        float wr = Wr[k * FEAT + j];
        const float4* xc = reinterpret_cast<const float4*>(&xsT[k * XS_STRIDE]);
        float4 x0 = xc[0], x1 = xc[1], x2 = xc[2], x3 = xc[3];
        const float* xv0 = reinterpret_cast<const float*>(&x0);
        const float* xv1 = reinterpret_cast<const float*>(&x1);
        const float* xv2 = reinterpret_cast<const float*>(&x2);
        const float* xv3 = reinterpret_cast<const float*>(&x3);
#pragma unroll
        for (int r = 0; r < 4; r++) { al[r]    += xv0[r] * wl; ar[r]    += xv0[r] * wr; }
#pragma unroll
        for (int r = 0; r < 4; r++) { al[4+r]  += xv1[r] * wl; ar[4+r]  += xv1[r] * wr; }
#pragma unroll
        for (int r = 0; r < 4; r++) { al[8+r]  += xv2[r] * wl; ar[8+r]  += xv2[r] * wr; }
#pragma unroll
        for (int r = 0; r < 4; r++) { al[12+r] += xv3[r] * wl; ar[12+r] += xv3[r] * wr; }
    }

    for (int r = 0; r < nrows; r++) {
        xl[(size_t)(row0 + r) * FEAT + j] = al[r];
        xr[(size_t)(row0 + r) * FEAT + j] = ar[r];
    }
}

// ---------------- per-node fused gather: score + softmax + aggregate + residual ----------------
// One block (192 threads) per node; thread j owns output channel j; head = j>>5.
// Heads are 32-lane aligned within waves -> __shfl_xor(...,32) reduces each head group.
__global__ __launch_bounds__(192) void k_node(const int* __restrict__ ei,
                                              const float* __restrict__ ew,
                                              const float* __restrict__ att,
                                              const float* __restrict__ We,
                                              const float* __restrict__ x,
                                              const float* __restrict__ bias,
                                              const int* __restrict__ start,
                                              const int* __restrict__ deg,
                                              const int* __restrict__ col,
                                              const float* __restrict__ xl,
                                              const float* __restrict__ xr,
                                              float* __restrict__ out) {
    int n = blockIdx.x;
    int j = threadIdx.x;
    float att_j = att[j];
    float We_j  = We[j];
    float xr_j  = xr[(size_t)n * FEAT + j];

    int beg = start[n];
    int dg  = deg[n];

    float acc = 0.f, den = 0.f, wsum = 0.f;
    for (int i = 0; i < dg; i++) {
        int e = col[beg + i];           // uniform per block (broadcast)
        int s = ei[e];
        float w = ew[e];
        float xlv = xl[(size_t)s * FEAT + j];
        float m = xlv + xr_j + w * We_j;
        m = (m > 0.f) ? m : NEG_SLOPE * m;
        float p = m * att_j;
        p += __shfl_xor(p, 16, 32);
        p += __shfl_xor(p, 8, 32);
        p += __shfl_xor(p, 4, 32);
        p += __shfl_xor(p, 2, 32);
        p += __shfl_xor(p, 1, 32);      // all 32 lanes now hold head's alpha
        float ex = __expf(p);
        den += ex;
        acc += ex * xlv;
        wsum += w;
    }
    // self-loop: weight = mean of incoming edge weights (0 if deg==0)
    {
        float w = wsum / fmaxf((float)dg, 1.0f);
        float xlv = xl[(size_t)n * FEAT + j];
        float m = xlv + xr_j + w * We_j;
        m = (m > 0.f) ? m : NEG_SLOPE * m;
        float p = m * att_j;
        p += __shfl_xor(p, 16, 32);
        p += __shfl_xor(p, 8, 32);
        p += __shfl_xor(p, 4, 32);
        p += __shfl_xor(p, 2, 32);
        p += __shfl_xor(p, 1, 32);
        float ex = __expf(p);
        den += ex;
        acc += ex * xlv;
    }

    float v = x[(size_t)n * FEAT + j] + bias[j] + acc / den;
    out[(size_t)n * FEAT + j] = v > 0.f ? v : 0.f;
}

extern "C" void kernel_launch(void* const* d_in, const int* in_sizes, int n_in,
                              void* d_out, int out_size, void* d_ws, size_t ws_size,
                              hipStream_t stream) {
    const float* x    = (const float*)d_in[0];
    const int*   ei   = (const int*)d_in[1];
    const float* ew   = (const float*)d_in[2];
    const float* Wl   = (const float*)d_in[3];
    const float* bl   = (const float*)d_in[4];
    const float* Wr   = (const float*)d_in[5];
    const float* br   = (const float*)d_in[6];
    const float* We   = (const float*)d_in[7];
    const float* att  = (const float*)d_in[8];
    const float* bias = (const float*)d_in[9];
    float* out = (float*)d_out;

    float* wsf = (float*)d_ws;
    float* xl = wsf + OFF_XL;
    float* xr = wsf + OFF_XR;
    int* ip      = (int*)(wsf + IDX_BASE);
    int* deg     = ip;
    int* cursor  = ip + N_NODES;
    int* start   = ip + 2 * N_NODES;
    int* scan    = ip + 3 * N_NODES;
    int* bsums   = ip + 4 * N_NODES;
    int* boffs   = ip + 4 * N_NODES + 256;
    int* col     = ip + 4 * N_NODES + 512;

    // zero deg + cursor (adjacent)
    hipMemsetAsync(ip, 0, 2 * N_NODES * sizeof(int), stream);

    k_count  <<<(N_EDGES + 255) / 256, 256, 0, stream>>>(ei, deg);
    k_scan1  <<<NB_SCAN, 256, 0, stream>>>(deg, scan, bsums);
    k_scan2  <<<1, 256, 0, stream>>>(bsums, boffs);
    k_scan3  <<<(N_NODES + 255) / 256, 256, 0, stream>>>(scan, boffs, deg, start);
    k_scatter<<<(N_EDGES + 255) / 256, 256, 0, stream>>>(ei, start, cursor, col);

    k_gemm<<<(N_NODES + GROWS - 1) / GROWS, 192, 0, stream>>>(x, Wl, bl, Wr, br, xl, xr);

    k_node<<<N_NODES, 192, 0, stream>>>(ei, ew, att, We, x, bias,
                                        start, deg, col, xl, xr, out);
}

// Round 4
// 383.258 us; speedup vs baseline: 12.5209x; 1.0821x over previous
//
#include <hip/hip_runtime.h>
#include <hip/hip_bf16.h>
#include <math.h>

#define N_NODES 50000
#define N_EDGES 400000
#define HEADS 6
#define DIMS 32
#define FEAT 192
#define NEG_SLOPE 0.2f

// ---------------- workspace layout ----------------
// floats: [xl: N*192][xr: N*192][w_sorted: E]
// ints (after): [deg: N][cursor: N][scan: N][bsums: 256][boffs: 256][src_sorted: E]
#define OFF_XL 0
#define OFF_XR (N_NODES * FEAT)
#define OFF_WSORT (N_NODES * FEAT * 2)
#define IDX_BASE (N_NODES * FEAT * 2 + N_EDGES)
#define NB_SCAN ((N_NODES + 255) / 256)   // 196

// ---------------- CSR build ----------------
__global__ __launch_bounds__(256) void k_count(const int* __restrict__ ei,
                                               int* __restrict__ deg) {
    int e = blockIdx.x * blockDim.x + threadIdx.x;
    if (e < N_EDGES) atomicAdd(&deg[ei[N_EDGES + e]], 1);
}

__global__ __launch_bounds__(256) void k_scan1(const int* __restrict__ deg,
                                               int* __restrict__ scan,
                                               int* __restrict__ bsums) {
    int t = threadIdx.x;
    int i = blockIdx.x * 256 + t;
    int v = (i < N_NODES) ? deg[i] : 0;
    __shared__ int s[256];
    s[t] = v; __syncthreads();
    for (int off = 1; off < 256; off <<= 1) {
        int u = (t >= off) ? s[t - off] : 0;
        __syncthreads();
        s[t] += u;
        __syncthreads();
    }
    if (i < N_NODES) scan[i] = s[t];   // inclusive within block
    if (t == 255) bsums[blockIdx.x] = s[255];
}

__global__ __launch_bounds__(256) void k_scan2(int* __restrict__ bsums,
                                               int* __restrict__ boffs) {
    int t = threadIdx.x;
    int v = (t < NB_SCAN) ? bsums[t] : 0;
    __shared__ int s[256];
    s[t] = v; __syncthreads();
    for (int off = 1; off < 256; off <<= 1) {
        int u = (t >= off) ? s[t - off] : 0;
        __syncthreads();
        s[t] += u;
        __syncthreads();
    }
    boffs[t] = s[t] - v;   // exclusive block offsets
}

// scatter: CSR stores payload (src node, weight) directly; start computed inline
__global__ __launch_bounds__(256) void k_scatter(const int* __restrict__ ei,
                                                 const float* __restrict__ ew,
                                                 const int* __restrict__ scan,
                                                 const int* __restrict__ boffs,
                                                 const int* __restrict__ deg,
                                                 int* __restrict__ cursor,
                                                 int* __restrict__ src_sorted,
                                                 float* __restrict__ w_sorted) {
    int e = blockIdx.x * blockDim.x + threadIdx.x;
    if (e < N_EDGES) {
        int d = ei[N_EDGES + e];
        int start = scan[d] + boffs[d >> 8] - deg[d];
        int slot = atomicAdd(&cursor[d], 1);
        src_sorted[start + slot] = ei[e];
        w_sorted[start + slot] = ew[e];
    }
}

// ---------------- xl = x@Wl + bl, xr = x@Wr + br ----------------
// 192 threads = one output column each; 32 rows register-blocked per thread.
#define GROWS 32
#define XS_STRIDE 36   // multiple of 4 -> 16B-aligned float4 reads
__global__ __launch_bounds__(192) void k_gemm(const float* __restrict__ x,
                                              const float* __restrict__ Wl,
                                              const float* __restrict__ bl,
                                              const float* __restrict__ Wr,
                                              const float* __restrict__ br,
                                              float* __restrict__ xl,
                                              float* __restrict__ xr) {
    __shared__ float xsT[FEAT * XS_STRIDE];  // xsT[k*36 + r] = x[row0+r][k]
    int j = threadIdx.x;                      // output column 0..191
    int row0 = blockIdx.x * GROWS;
    int nrows = N_NODES - row0; if (nrows > GROWS) nrows = GROWS;
    for (int r = 0; r < nrows; r++) {
        xsT[j * XS_STRIDE + r] = x[(size_t)(row0 + r) * FEAT + j];
    }
    __syncthreads();

    float al[GROWS], ar[GROWS];
    float blj = bl[j], brj = br[j];
#pragma unroll
    for (int r = 0; r < GROWS; r++) { al[r] = blj; ar[r] = brj; }

    for (int k = 0; k < FEAT; k++) {
        float wl = Wl[k * FEAT + j];
        float wr = Wr[k * FEAT + j];
        const float4* xc = reinterpret_cast<const float4*>(&xsT[k * XS_STRIDE]);
#pragma unroll
        for (int q = 0; q < 8; q++) {
            float4 xq = xc[q];
            const float* xv = reinterpret_cast<const float*>(&xq);
#pragma unroll
            for (int u = 0; u < 4; u++) {
                int r = q * 4 + u;
                al[r] += xv[u] * wl;
                ar[r] += xv[u] * wr;
            }
        }
    }

    for (int r = 0; r < nrows; r++) {
        xl[(size_t)(row0 + r) * FEAT + j] = al[r];
        xr[(size_t)(row0 + r) * FEAT + j] = ar[r];
    }
}

// ---------------- per-node fused gather: score + softmax + aggregate + residual ----------------
// One block (192 threads) per node; thread j owns channel j; head = j>>5 (32-lane aligned).
// Edge list staged in LDS; xl gather software-pipelined one iteration ahead.
#define CHUNK 192
__global__ __launch_bounds__(192) void k_node(const float* __restrict__ att,
                                              const float* __restrict__ We,
                                              const float* __restrict__ x,
                                              const float* __restrict__ bias,
                                              const int* __restrict__ scan,
                                              const int* __restrict__ boffs,
                                              const int* __restrict__ deg,
                                              const int* __restrict__ src_sorted,
                                              const float* __restrict__ w_sorted,
                                              const float* __restrict__ xl,
                                              const float* __restrict__ xr,
                                              float* __restrict__ out) {
    __shared__ int   sS[CHUNK];
    __shared__ float sW[CHUNK];
    int n = blockIdx.x;
    int j = threadIdx.x;
    float att_j = att[j];
    float We_j  = We[j];
    float xr_j  = xr[(size_t)n * FEAT + j];

    int dg  = deg[n];
    int beg = scan[n] + boffs[n >> 8] - dg;

    float acc = 0.f, den = 0.f, wsum = 0.f;
    for (int i0 = 0; i0 < dg; i0 += CHUNK) {
        int c = dg - i0; if (c > CHUNK) c = CHUNK;
        if (j < c) {
            sS[j] = src_sorted[beg + i0 + j];
            sW[j] = w_sorted[beg + i0 + j];
        }
        __syncthreads();
        float xln = xl[(size_t)sS[0] * FEAT + j];   // prefetch edge 0
        for (int i = 0; i < c; i++) {
            float xlv = xln;
            if (i + 1 < c) xln = xl[(size_t)sS[i + 1] * FEAT + j];  // prefetch next
            float w = sW[i];
            float m = xlv + xr_j + w * We_j;
            m = (m > 0.f) ? m : NEG_SLOPE * m;
            float p = m * att_j;
            p += __shfl_xor(p, 16, 32);
            p += __shfl_xor(p, 8, 32);
            p += __shfl_xor(p, 4, 32);
            p += __shfl_xor(p, 2, 32);
            p += __shfl_xor(p, 1, 32);   // head-wide alpha in all 32 lanes
            float ex = __expf(p);
            den += ex;
            acc += ex * xlv;
            wsum += w;
        }
        __syncthreads();
    }
    // self-loop: weight = mean of incoming edge weights (0 if deg==0)
    {
        float w = wsum / fmaxf((float)dg, 1.0f);
        float xlv = xl[(size_t)n * FEAT + j];
        float m = xlv + xr_j + w * We_j;
        m = (m > 0.f) ? m : NEG_SLOPE * m;
        float p = m * att_j;
        p += __shfl_xor(p, 16, 32);
        p += __shfl_xor(p, 8, 32);
        p += __shfl_xor(p, 4, 32);
        p += __shfl_xor(p, 2, 32);
        p += __shfl_xor(p, 1, 32);
        float ex = __expf(p);
        den += ex;
        acc += ex * xlv;
    }

    float v = x[(size_t)n * FEAT + j] + bias[j] + acc / den;
    out[(size_t)n * FEAT + j] = v > 0.f ? v : 0.f;
}

extern "C" void kernel_launch(void* const* d_in, const int* in_sizes, int n_in,
                              void* d_out, int out_size, void* d_ws, size_t ws_size,
                              hipStream_t stream) {
    const float* x    = (const float*)d_in[0];
    const int*   ei   = (const int*)d_in[1];
    const float* ew   = (const float*)d_in[2];
    const float* Wl   = (const float*)d_in[3];
    const float* bl   = (const float*)d_in[4];
    const float* Wr   = (const float*)d_in[5];
    const float* br   = (const float*)d_in[6];
    const float* We   = (const float*)d_in[7];
    const float* att  = (const float*)d_in[8];
    const float* bias = (const float*)d_in[9];
    float* out = (float*)d_out;

    float* wsf = (float*)d_ws;
    float* xl       = wsf + OFF_XL;
    float* xr       = wsf + OFF_XR;
    float* w_sorted = wsf + OFF_WSORT;
    int* ip         = (int*)(wsf + IDX_BASE);
    int* deg        = ip;
    int* cursor     = ip + N_NODES;
    int* scan       = ip + 2 * N_NODES;
    int* bsums      = ip + 3 * N_NODES;
    int* boffs      = ip + 3 * N_NODES + 256;
    int* src_sorted = ip + 3 * N_NODES + 512;

    // zero deg + cursor (adjacent); harness poisons ws with 0xAA
    hipMemsetAsync(ip, 0, 2 * N_NODES * sizeof(int), stream);

    k_count  <<<(N_EDGES + 255) / 256, 256, 0, stream>>>(ei, deg);
    k_scan1  <<<NB_SCAN, 256, 0, stream>>>(deg, scan, bsums);
    k_scan2  <<<1, 256, 0, stream>>>(bsums, boffs);
    k_scatter<<<(N_EDGES + 255) / 256, 256, 0, stream>>>(ei, ew, scan, boffs, deg,
                                                         cursor, src_sorted, w_sorted);

    k_gemm<<<(N_NODES + GROWS - 1) / GROWS, 192, 0, stream>>>(x, Wl, bl, Wr, br, xl, xr);

    k_node<<<N_NODES, 192, 0, stream>>>(att, We, x, bias, scan, boffs, deg,
                                        src_sorted, w_sorted, xl, xr, out);
}

// Round 5
// 350.180 us; speedup vs baseline: 13.7036x; 1.0945x over previous
//
#include <hip/hip_runtime.h>
#include <hip/hip_bf16.h>
#include <math.h>

#define N_NODES 50000
#define N_EDGES 400000
#define HEADS 6
#define DIMS 32
#define FEAT 192
#define NEG_SLOPE 0.2f

typedef __attribute__((ext_vector_type(8))) short short8;
typedef __attribute__((ext_vector_type(4))) float f32x4;

__device__ __forceinline__ unsigned short f2bu(float f) {
    __hip_bfloat16 h = __float2bfloat16(f);
    unsigned short u; __builtin_memcpy(&u, &h, 2); return u;
}
__device__ __forceinline__ float bu2f(unsigned short u) {
    return __uint_as_float(((unsigned)u) << 16);
}

// ---------------- workspace layout (byte offsets) ----------------
// xl_bf (ushort N*192), xr_bf (ushort N*192), Wt (short 384*192), blr (float 384),
// pair (int2 E), deg/cursor/scan (int N each), bsums/boffs (int 256 each)
#define XL_OFF   0
#define XR_OFF   19200000
#define WT_OFF   38400000
#define BLR_OFF  38547456
#define PAIR_OFF 38548992
#define DEG_OFF  41748992
#define CUR_OFF  41948992
#define SCAN_OFF 42148992
#define BSUM_OFF 42348992
#define BOFF_OFF 42350016
#define NB_SCAN ((N_NODES + 255) / 256)   // 196

// ---------------- CSR build ----------------
__global__ __launch_bounds__(256) void k_count(const int* __restrict__ ei,
                                               int* __restrict__ deg) {
    int e = blockIdx.x * blockDim.x + threadIdx.x;
    if (e < N_EDGES) atomicAdd(&deg[ei[N_EDGES + e]], 1);
}

__global__ __launch_bounds__(256) void k_scan1(const int* __restrict__ deg,
                                               int* __restrict__ scan,
                                               int* __restrict__ bsums) {
    int t = threadIdx.x;
    int i = blockIdx.x * 256 + t;
    int v = (i < N_NODES) ? deg[i] : 0;
    __shared__ int s[256];
    s[t] = v; __syncthreads();
    for (int off = 1; off < 256; off <<= 1) {
        int u = (t >= off) ? s[t - off] : 0;
        __syncthreads();
        s[t] += u;
        __syncthreads();
    }
    if (i < N_NODES) scan[i] = s[t];   // inclusive within block
    if (t == 255) bsums[blockIdx.x] = s[255];
}

__global__ __launch_bounds__(256) void k_scan2(int* __restrict__ bsums,
                                               int* __restrict__ boffs) {
    int t = threadIdx.x;
    int v = (t < NB_SCAN) ? bsums[t] : 0;
    __shared__ int s[256];
    s[t] = v; __syncthreads();
    for (int off = 1; off < 256; off <<= 1) {
        int u = (t >= off) ? s[t - off] : 0;
        __syncthreads();
        s[t] += u;
        __syncthreads();
    }
    boffs[t] = s[t] - v;   // exclusive block offsets
}

// scatter edge payload (src, weight-bits) into CSR slots
__global__ __launch_bounds__(256) void k_scatter(const int* __restrict__ ei,
                                                 const float* __restrict__ ew,
                                                 const int* __restrict__ scan,
                                                 const int* __restrict__ boffs,
                                                 const int* __restrict__ deg,
                                                 int* __restrict__ cursor,
                                                 int2* __restrict__ pair) {
    int e = blockIdx.x * blockDim.x + threadIdx.x;
    if (e < N_EDGES) {
        int d = ei[N_EDGES + e];
        int st = scan[d] + boffs[d >> 8] - deg[d];
        int slot = atomicAdd(&cursor[d], 1);
        int2 p; p.x = ei[e]; p.y = __float_as_int(ew[e]);
        pair[st + slot] = p;
    }
}

// ---------------- pack Wt[n][k] = W[k][n] (bf16) + blr ----------------
__global__ __launch_bounds__(256) void k_pack(const float* __restrict__ Wl,
                                              const float* __restrict__ Wr,
                                              const float* __restrict__ bl,
                                              const float* __restrict__ br,
                                              short* __restrict__ Wt,
                                              float* __restrict__ blr) {
    int t = blockIdx.x * blockDim.x + threadIdx.x;
    if (t < 384 * FEAT) {
        int n = t / FEAT, k = t - n * FEAT;
        float v = (n < FEAT) ? Wl[k * FEAT + n] : Wr[k * FEAT + (n - FEAT)];
        Wt[n * FEAT + k] = (short)f2bu(v);
    }
    if (t < 384) blr[t] = (t < FEAT) ? bl[t] : br[t - FEAT];
}

// ---------------- MFMA GEMM: [xl|xr] = x @ [Wl|Wr] + [bl|br], bf16 out ----------------
// Block = 6 waves; block M-tile = 16 rows; wave w covers cols [w*64, w*64+64).
// A-frag: row m=lane&15, k = kstep*32 + (lane>>4)*8 + i  (fp32 load + in-reg bf16 cvt)
// B-frag: col n=lane&15 (of tile), same k range; Wt[n][k] storage -> contiguous 16B.
// C/D: col=lane&15, row=(lane>>4)*4+reg  [measured m89/m91]
__global__ __launch_bounds__(384) void k_gemm_mfma(const float* __restrict__ x,
                                                   const short* __restrict__ Wt,
                                                   const float* __restrict__ blr,
                                                   unsigned short* __restrict__ xl,
                                                   unsigned short* __restrict__ xr) {
    int wv   = threadIdx.x >> 6;
    int lane = threadIdx.x & 63;
    int m    = lane & 15;
    int kg   = lane >> 4;            // 0..3
    size_t row0 = (size_t)blockIdx.x * 16;
    int ncol0 = wv * 64;

    f32x4 acc0 = {0.f,0.f,0.f,0.f}, acc1 = acc0, acc2 = acc0, acc3 = acc0;

#pragma unroll
    for (int ks = 0; ks < 6; ks++) {
        int kb = ks * 32 + kg * 8;
        const float* ap = x + (row0 + m) * FEAT + kb;
        float4 a0 = *(const float4*)ap;
        float4 a1 = *(const float4*)(ap + 4);
        short8 af;
        af[0] = (short)f2bu(a0.x); af[1] = (short)f2bu(a0.y);
        af[2] = (short)f2bu(a0.z); af[3] = (short)f2bu(a0.w);
        af[4] = (short)f2bu(a1.x); af[5] = (short)f2bu(a1.y);
        af[6] = (short)f2bu(a1.z); af[7] = (short)f2bu(a1.w);
        const short* wp = Wt + (size_t)(ncol0 + m) * FEAT + kb;
        short8 b0 = *(const short8*)(wp);
        short8 b1 = *(const short8*)(wp + 16 * FEAT);
        short8 b2 = *(const short8*)(wp + 32 * FEAT);
        short8 b3 = *(const short8*)(wp + 48 * FEAT);
        acc0 = __builtin_amdgcn_mfma_f32_16x16x32_bf16(af, b0, acc0, 0, 0, 0);
        acc1 = __builtin_amdgcn_mfma_f32_16x16x32_bf16(af, b1, acc1, 0, 0, 0);
        acc2 = __builtin_amdgcn_mfma_f32_16x16x32_bf16(af, b2, acc2, 0, 0, 0);
        acc3 = __builtin_amdgcn_mfma_f32_16x16x32_bf16(af, b3, acc3, 0, 0, 0);
    }

    size_t orow = row0 + kg * 4;
    f32x4 accs[4] = {acc0, acc1, acc2, acc3};
#pragma unroll
    for (int t = 0; t < 4; t++) {
        int col = ncol0 + t * 16 + m;
        float bv = blr[col];
        unsigned short* dst = (col < FEAT) ? xl : xr;   // uniform per wave
        int c2 = (col < FEAT) ? col : col - FEAT;
#pragma unroll
        for (int r = 0; r < 4; r++) {
            dst[(orow + r) * FEAT + c2] = f2bu(accs[t][r] + bv);
        }
    }
}

// ---------------- per-node fused gather: score + softmax + aggregate + residual ----------------
#define CHUNK 192
__global__ __launch_bounds__(192) void k_node(const float* __restrict__ att,
                                              const float* __restrict__ We,
                                              const float* __restrict__ x,
                                              const float* __restrict__ bias,
                                              const int* __restrict__ scan,
                                              const int* __restrict__ boffs,
                                              const int* __restrict__ deg,
                                              const int2* __restrict__ pair,
                                              const unsigned short* __restrict__ xl,
                                              const unsigned short* __restrict__ xr,
                                              float* __restrict__ out) {
    __shared__ int2 sE[CHUNK];
    int n = blockIdx.x;
    int j = threadIdx.x;
    float att_j = att[j];
    float We_j  = We[j];
    float xr_j  = bu2f(xr[(size_t)n * FEAT + j]);

    int dg  = deg[n];
    int beg = scan[n] + boffs[n >> 8] - dg;

    float acc = 0.f, den = 0.f, wsum = 0.f;
    for (int i0 = 0; i0 < dg; i0 += CHUNK) {
        int c = dg - i0; if (c > CHUNK) c = CHUNK;
        if (j < c) sE[j] = pair[beg + i0 + j];
        __syncthreads();
        int2 e0 = sE[0];
        float xln = bu2f(xl[(size_t)e0.x * FEAT + j]);   // prefetch edge 0
        float wn  = __int_as_float(e0.y);
        for (int i = 0; i < c; i++) {
            float xlv = xln, w = wn;
            if (i + 1 < c) {
                int2 en = sE[i + 1];
                xln = bu2f(xl[(size_t)en.x * FEAT + j]); // prefetch next
                wn  = __int_as_float(en.y);
            }
            float m = xlv + xr_j + w * We_j;
            m = (m > 0.f) ? m : NEG_SLOPE * m;
            float p = m * att_j;
            p += __shfl_xor(p, 16, 32);
            p += __shfl_xor(p, 8, 32);
            p += __shfl_xor(p, 4, 32);
            p += __shfl_xor(p, 2, 32);
            p += __shfl_xor(p, 1, 32);   // head-wide alpha in all 32 lanes
            float ex = __expf(p);
            den += ex;
            acc += ex * xlv;
            wsum += w;
        }
        __syncthreads();
    }
    // self-loop: weight = mean of incoming edge weights (0 if deg==0)
    {
        float w = wsum / fmaxf((float)dg, 1.0f);
        float xlv = bu2f(xl[(size_t)n * FEAT + j]);
        float m = xlv + xr_j + w * We_j;
        m = (m > 0.f) ? m : NEG_SLOPE * m;
        float p = m * att_j;
        p += __shfl_xor(p, 16, 32);
        p += __shfl_xor(p, 8, 32);
        p += __shfl_xor(p, 4, 32);
        p += __shfl_xor(p, 2, 32);
        p += __shfl_xor(p, 1, 32);
        float ex = __expf(p);
        den += ex;
        acc += ex * xlv;
    }

    float v = x[(size_t)n * FEAT + j] + bias[j] + acc / den;
    out[(size_t)n * FEAT + j] = v > 0.f ? v : 0.f;
}

extern "C" void kernel_launch(void* const* d_in, const int* in_sizes, int n_in,
                              void* d_out, int out_size, void* d_ws, size_t ws_size,
                              hipStream_t stream) {
    const float* x    = (const float*)d_in[0];
    const int*   ei   = (const int*)d_in[1];
    const float* ew   = (const float*)d_in[2];
    const float* Wl   = (const float*)d_in[3];
    const float* bl   = (const float*)d_in[4];
    const float* Wr   = (const float*)d_in[5];
    const float* br   = (const float*)d_in[6];
    const float* We   = (const float*)d_in[7];
    const float* att  = (const float*)d_in[8];
    const float* bias = (const float*)d_in[9];
    float* out = (float*)d_out;

    char* ws = (char*)d_ws;
    unsigned short* xl = (unsigned short*)(ws + XL_OFF);
    unsigned short* xr = (unsigned short*)(ws + XR_OFF);
    short* Wt    = (short*)(ws + WT_OFF);
    float* blr   = (float*)(ws + BLR_OFF);
    int2*  pair  = (int2*)(ws + PAIR_OFF);
    int*   deg   = (int*)(ws + DEG_OFF);
    int*   cursor= (int*)(ws + CUR_OFF);
    int*   scan  = (int*)(ws + SCAN_OFF);
    int*   bsums = (int*)(ws + BSUM_OFF);
    int*   boffs = (int*)(ws + BOFF_OFF);

    // zero deg + cursor (adjacent); harness poisons ws with 0xAA
    hipMemsetAsync(ws + DEG_OFF, 0, 2 * N_NODES * sizeof(int), stream);

    k_count  <<<(N_EDGES + 255) / 256, 256, 0, stream>>>(ei, deg);
    k_scan1  <<<NB_SCAN, 256, 0, stream>>>(deg, scan, bsums);
    k_scan2  <<<1, 256, 0, stream>>>(bsums, boffs);
    k_scatter<<<(N_EDGES + 255) / 256, 256, 0, stream>>>(ei, ew, scan, boffs, deg,
                                                         cursor, pair);
    k_pack   <<<(384 * FEAT + 255) / 256, 256, 0, stream>>>(Wl, Wr, bl, br, Wt, blr);

    k_gemm_mfma<<<N_NODES / 16, 384, 0, stream>>>(x, Wt, blr, xl, xr);

    k_node<<<N_NODES, 192, 0, stream>>>(att, We, x, bias, scan, boffs, deg,
                                        pair, xl, xr, out);
}